// Round 4
// baseline (333.161 us; speedup 1.0000x reference)
//
#include <hip/hip_runtime.h>
#include <hip/hip_bf16.h>
#include <stdint.h>

#define S_LEN 2048
#define E_DIM 128
#define QT 64
#define KT 64

typedef __attribute__((ext_vector_type(4))) float f32x4;
typedef __attribute__((ext_vector_type(4))) short s16x4;
typedef __attribute__((ext_vector_type(8))) short bf16x8;

__device__ __forceinline__ short f2bf(float f) {
    uint32_t u = __builtin_bit_cast(uint32_t, f);
    u += 0x7FFFu + ((u >> 16) & 1u);
    return (short)(u >> 16);
}
__device__ __forceinline__ float bf2f(short h) {
    uint32_t u = ((uint32_t)(uint16_t)h) << 16;
    return __builtin_bit_cast(float, u);
}

// Threefry-2x32 (generic key) — matches jax._src.prng.threefry2x32
__device__ __forceinline__ void threefry_g(uint32_t k0, uint32_t k1,
                                           uint32_t c0, uint32_t c1,
                                           uint32_t& y0, uint32_t& y1) {
    uint32_t ks2 = k0 ^ k1 ^ 0x1BD11BDAu;
    uint32_t x0 = c0 + k0, x1 = c1 + k1;
#define TF_R(rr) { x0 += x1; x1 = (x1 << rr) | (x1 >> (32 - rr)); x1 ^= x0; }
    TF_R(13) TF_R(15) TF_R(26) TF_R(6)
    x0 += k1;  x1 += ks2 + 1u;
    TF_R(17) TF_R(29) TF_R(16) TF_R(24)
    x0 += ks2; x1 += k0 + 2u;
    TF_R(13) TF_R(15) TF_R(26) TF_R(6)
    x0 += k0;  x1 += k1 + 3u;
    TF_R(17) TF_R(29) TF_R(16) TF_R(24)
    x0 += k1;  x1 += ks2 + 4u;
    TF_R(13) TF_R(15) TF_R(26) TF_R(6)
    x0 += ks2; x1 += k0 + 5u;
#undef TF_R
    y0 = x0; y1 = x1;
}

// keep-bit, flat index j over (16,2048,2048), key(42), p=0.9.
// Modern JAX default: jax_threefry_partitionable=True, x64 off:
//   per-element 64-bit counter -> threefry2x32(key, (j>>32, j&0xffffffff));
//   32-bit draw = y0 ^ y1; uniform = ((draw>>9)|0x3f800000) - 1 < 0.9f
//   <=> draw < 0xE6666600  (0.9f = 7549747 / 2^23)
__device__ __forceinline__ bool keep_bit(uint32_t j) {
    uint32_t y0, y1;
    threefry_g(0u, 42u, 0u, j, y0, y1);
    return (y0 ^ y1) < 0xE6666600u;
}

__global__ __launch_bounds__(256, 2)
void attn_fwd(const float* __restrict__ Qg, const float* __restrict__ Kg,
              const float* __restrict__ Vg, float* __restrict__ Og) {
    __shared__ short kh[QT * E_DIM];      // 16 KB, swizzled ^((row&7)<<3) elem
    __shared__ short kl[QT * E_DIM];      // 16 KB
    __shared__ short vt[E_DIM * 66];      // 16.5 KB, V^T, row stride 66 elems
    __shared__ short pl[4][16 * 64];      // 8 KB, per-wave P tiles, swizzled

    const int tid = threadIdx.x;
    const int w   = tid >> 6;
    const int ln  = tid & 63;
    const int r   = ln & 15;
    const int g   = ln >> 4;
    const int bid = blockIdx.x;
    const int b   = bid >> 5;
    const int q0  = (bid & 31) << 6;
    const size_t boff = (size_t)b * S_LEN * E_DIM;

    // ---------- self-tests (certify threefry + MFMA layouts; plant on fail) --
    bool kat1 = true, kat3 = true;
    int mfma_ok = 1;
    if (bid == 0 && w == 0) {
        uint32_t a0, a1;
        threefry_g(0u, 0u, 0u, 0u, a0, a1);
        kat1 = (a0 == 0x6b200159u && a1 == 0x99ba4efeu);
        threefry_g(0x13198a2eu, 0x03707344u, 0x243f6a88u, 0x85a308d3u, a0, a1);
        kat3 = (a0 == 0xc4923a9cu && a1 == 0x483df7a0u);
        bf16x8 af, bfr;
        #pragma unroll
        for (int i = 0; i < 8; ++i) {
            int k = g * 8 + i;
            af[i]  = f2bf((float)((r * 5 + k * 3) & 7));
            bfr[i] = f2bf((float)((k + r * 3) & 7));
        }
        f32x4 pc = {0.f, 0.f, 0.f, 0.f};
        pc = __builtin_amdgcn_mfma_f32_16x16x32_bf16(af, bfr, pc, 0, 0, 0);
        int ok = 1;
        #pragma unroll
        for (int j2 = 0; j2 < 4; ++j2) {
            int row = g * 4 + j2, col = r;
            float ex = 0.f;
            for (int k = 0; k < 32; ++k)
                ex += (float)((row * 5 + k * 3) & 7) * (float)((k + col * 3) & 7);
            if (pc[j2] != ex) ok = 0;
        }
        mfma_ok = __all(ok);
    }

    // ---- stage Q (rows q0..q0+63) into kh/kl as split bf16 ----
    {
        const float* src = Qg + boff + (size_t)q0 * E_DIM;
        const int e0 = (tid & 31) * 4;
        const int rb = tid >> 5;
        #pragma unroll
        for (int it = 0; it < 8; ++it) {
            int row = it * 8 + rb;
            f32x4 v = *(const f32x4*)(src + row * E_DIM + e0);
            s16x4 h, lo;
            #pragma unroll
            for (int i = 0; i < 4; ++i) {
                short hh = f2bf(v[i]);
                h[i]  = hh;
                lo[i] = f2bf(v[i] - bf2f(hh));
            }
            int idx = (row * E_DIM + e0) ^ ((row & 7) << 3);
            *(s16x4*)(kh + idx) = h;
            *(s16x4*)(kl + idx) = lo;
        }
    }
    __syncthreads();

    // ---- preload Q fragments (A-frag: lane holds row=ln&15, k=8*(ln>>4)+i) --
    bf16x8 qh[4], ql[4];
    {
        int row = w * 16 + r;
        #pragma unroll
        for (int ec = 0; ec < 4; ++ec) {
            int idx = (row * E_DIM + ec * 32 + g * 8) ^ ((row & 7) << 3);
            qh[ec] = *(const bf16x8*)(kh + idx);
            ql[ec] = *(const bf16x8*)(kl + idx);
        }
    }

    f32x4 oacc[8];
    #pragma unroll
    for (int i = 0; i < 8; ++i) oacc[i] = f32x4{0.f, 0.f, 0.f, 0.f};
    float mrun[4] = {-1e30f, -1e30f, -1e30f, -1e30f};
    float den[4]  = {0.f, 0.f, 0.f, 0.f};

    for (int kt = 0; kt < S_LEN / KT; ++kt) {
        __syncthreads();   // prior LDS consumers done (incl. Q preload at kt=0)
        // ---- stage K tile (split bf16) ----
        {
            const float* src = Kg + boff + (size_t)(kt * KT) * E_DIM;
            const int e0 = (tid & 31) * 4;
            const int rb = tid >> 5;
            #pragma unroll
            for (int it = 0; it < 8; ++it) {
                int row = it * 8 + rb;
                f32x4 v = *(const f32x4*)(src + row * E_DIM + e0);
                s16x4 h, lo;
                #pragma unroll
                for (int i = 0; i < 4; ++i) {
                    short hh = f2bf(v[i]);
                    h[i]  = hh;
                    lo[i] = f2bf(v[i] - bf2f(hh));
                }
                int idx = (row * E_DIM + e0) ^ ((row & 7) << 3);
                *(s16x4*)(kh + idx) = h;
                *(s16x4*)(kl + idx) = lo;
            }
        }
        // ---- stage V tile, transposed: vt[e][k], row stride 66 elems ----
        {
            const float* src = Vg + boff + (size_t)(kt * KT) * E_DIM;
            const int e0 = (tid & 31) * 4;
            const int kb = (tid >> 5) * 2;
            #pragma unroll
            for (int it = 0; it < 4; ++it) {
                int k = it * 16 + kb;
                f32x4 a  = *(const f32x4*)(src + k * E_DIM + e0);
                f32x4 c2 = *(const f32x4*)(src + (k + 1) * E_DIM + e0);
                #pragma unroll
                for (int ci = 0; ci < 4; ++ci) {
                    uint32_t pack = (uint32_t)(uint16_t)f2bf(a[ci]) |
                                    ((uint32_t)(uint16_t)f2bf(c2[ci]) << 16);
                    *(uint32_t*)(vt + (e0 + ci) * 66 + k) = pack;
                }
            }
        }
        __syncthreads();

        // ---- S = Q K^T (16 rows x 64 cols per wave), 3-MFMA bf16 split ----
        f32x4 sc[4];
        #pragma unroll
        for (int c = 0; c < 4; ++c) {
            f32x4 acc = f32x4{0.f, 0.f, 0.f, 0.f};
            int krow = c * 16 + r;
            int sw = (krow & 7) << 3;
            #pragma unroll
            for (int ec = 0; ec < 4; ++ec) {
                int idx = (krow * E_DIM + ec * 32 + g * 8) ^ sw;
                bf16x8 bh = *(const bf16x8*)(kh + idx);
                bf16x8 bl = *(const bf16x8*)(kl + idx);
                acc = __builtin_amdgcn_mfma_f32_16x16x32_bf16(qh[ec], bh, acc, 0, 0, 0);
                acc = __builtin_amdgcn_mfma_f32_16x16x32_bf16(ql[ec], bh, acc, 0, 0, 0);
                acc = __builtin_amdgcn_mfma_f32_16x16x32_bf16(qh[ec], bl, acc, 0, 0, 0);
            }
            sc[c] = acc;
        }

        // ---- online softmax (row = g*4 + reg lives on 16 lanes of same g) ---
        float scale[4];
        #pragma unroll
        for (int reg = 0; reg < 4; ++reg) {
            float v0 = fmaxf(fmaxf(sc[0][reg], sc[1][reg]),
                             fmaxf(sc[2][reg], sc[3][reg]));
            v0 = fmaxf(v0, __shfl_xor(v0, 1));
            v0 = fmaxf(v0, __shfl_xor(v0, 2));
            v0 = fmaxf(v0, __shfl_xor(v0, 4));
            v0 = fmaxf(v0, __shfl_xor(v0, 8));
            float mnew = fmaxf(mrun[reg], v0);
            scale[reg] = __expf(mrun[reg] - mnew);
            mrun[reg] = mnew;
        }
        float rs[4] = {0.f, 0.f, 0.f, 0.f};
        #pragma unroll
        for (int c = 0; c < 4; ++c) {
            #pragma unroll
            for (int reg = 0; reg < 4; ++reg) {
                float p = __expf(sc[c][reg] - mrun[reg]);
                sc[c][reg] = p;
                rs[reg] += p;
            }
        }
        #pragma unroll
        for (int reg = 0; reg < 4; ++reg) {
            float v0 = rs[reg];
            v0 += __shfl_xor(v0, 1);
            v0 += __shfl_xor(v0, 2);
            v0 += __shfl_xor(v0, 4);
            v0 += __shfl_xor(v0, 8);
            den[reg] = den[reg] * scale[reg] + v0;   // undropped denominator
        }
        #pragma unroll
        for (int et = 0; et < 8; ++et) {
            #pragma unroll
            for (int reg = 0; reg < 4; ++reg) oacc[et][reg] *= scale[reg];
        }

        // ---- dropout (JAX partitionable threefry, f32 path) + P to LDS ----
        #pragma unroll
        for (int c = 0; c < 4; ++c) {
            int kcol = kt * KT + c * 16 + r;
            #pragma unroll
            for (int reg = 0; reg < 4; ++reg) {
                int row = g * 4 + reg;
                uint32_t q = (uint32_t)(q0 + w * 16 + row);
                uint32_t j = (((uint32_t)b << 11) + q) * 2048u + (uint32_t)kcol;
                float pm = keep_bit(j) ? sc[c][reg] * (1.0f / 0.9f) : 0.0f;
                int idx = (row * 64 + (c * 16 + r)) ^ ((row & 7) << 3);
                pl[w][idx] = f2bf(pm);
            }
        }

        // ---- O += P V ----
        bf16x8 pa[2];
        #pragma unroll
        for (int st = 0; st < 2; ++st) {
            int idx = (r * 64 + st * 32 + g * 8) ^ ((r & 7) << 3);
            pa[st] = *(const bf16x8*)(&pl[w][0] + idx);
        }
        #pragma unroll
        for (int et = 0; et < 8; ++et) {
            int e = et * 16 + r;
            f32x4 o = oacc[et];
            #pragma unroll
            for (int st = 0; st < 2; ++st) {
                union { bf16x8 v; uint32_t u[4]; } vb;
                #pragma unroll
                for (int i2 = 0; i2 < 4; ++i2)
                    vb.u[i2] = *(const uint32_t*)(vt + e * 66 + st * 32 + g * 8 + i2 * 2);
                o = __builtin_amdgcn_mfma_f32_16x16x32_bf16(pa[st], vb.v, o, 0, 0, 0);
            }
            oacc[et] = o;
        }
    }

    // ---- epilogue ----
    float inv[4];
    #pragma unroll
    for (int reg = 0; reg < 4; ++reg) inv[reg] = 1.0f / den[reg];
    float* dst = Og + boff + (size_t)q0 * E_DIM;
    #pragma unroll
    for (int et = 0; et < 8; ++et) {
        #pragma unroll
        for (int reg = 0; reg < 4; ++reg) {
            int row = w * 16 + g * 4 + reg;
            int e = et * 16 + r;
            dst[row * E_DIM + e] = oacc[et][reg] * inv[reg];
        }
    }

    if (bid == 0 && tid == 0) {
        int plant = (kat1 ? 0 : 1000) + (kat3 ? 0 : 500) + (mfma_ok ? 0 : 250);
        if (plant) Og[0] = (float)plant;
    }
}

extern "C" void kernel_launch(void* const* d_in, const int* in_sizes, int n_in,
                              void* d_out, int out_size, void* d_ws, size_t ws_size,
                              hipStream_t stream) {
    (void)in_sizes; (void)n_in; (void)d_ws; (void)ws_size; (void)out_size;
    const float* Q = (const float*)d_in[0];
    const float* K = (const float*)d_in[1];
    const float* V = (const float*)d_in[2];
    float* O = (float*)d_out;
    hipLaunchKernelGGL(attn_fwd, dim3(16 * 32), dim3(256), 0, stream, Q, K, V, O);
}